// Round 17
// baseline (352.469 us; speedup 1.0000x reference)
//
#include <hip/hip_runtime.h>

// LoRALinear: out = x @ (W + 2 * B@A)^T + b
// r17: r16 with MFMA shape switched 16x16x32 -> 32x32x16 (µbench 2382 vs
// 2075 TF: +15% pipe rate, half the instruction count). Same LDS layout,
// staging, XCD chunking, schedule, W-A-R structure.

static constexpr int Mdim = 8192;
static constexpr int Ndim = 4096;
static constexpr int Kdim = 4096;
#define LORA_SCALE 2.0f   // alpha/rank = 32/16

typedef __bf16 bf16;
typedef __bf16 bf16x8 __attribute__((ext_vector_type(8)));
typedef __bf16 bf16x4 __attribute__((ext_vector_type(4)));
typedef float f32x16 __attribute__((ext_vector_type(16)));

__device__ __forceinline__ void gload_lds16(const void* g, void* l) {
  __builtin_amdgcn_global_load_lds(
      (const __attribute__((address_space(1))) unsigned int*)g,
      (__attribute__((address_space(3))) unsigned int*)l, 16, 0, 0);
}

// ---------------- fused prep: blocks [0,4096) cvt x; [4096,4608) fold W' ----------------
static constexpr int CVT_BLOCKS = 4096;

__global__ __launch_bounds__(256) void prep_kernel(const float* __restrict__ x,
                                                   bf16* __restrict__ xb,
                                                   const float* __restrict__ W,
                                                   const float* __restrict__ lA,
                                                   const float* __restrict__ lB,
                                                   bf16* __restrict__ wb) {
  const int t = threadIdx.x;
  if (blockIdx.x < CVT_BLOCKS) {
    const int n8 = Mdim * Kdim / 8;
    for (int i = blockIdx.x * 256 + t; i < n8; i += CVT_BLOCKS * 256) {
      const float4* p = reinterpret_cast<const float4*>(x) + (size_t)i * 2;
      float4 a = p[0];
      float4 c = p[1];
      bf16x8 o;
      o[0] = (bf16)a.x; o[1] = (bf16)a.y; o[2] = (bf16)a.z; o[3] = (bf16)a.w;
      o[4] = (bf16)c.x; o[5] = (bf16)c.y; o[6] = (bf16)c.z; o[7] = (bf16)c.w;
      reinterpret_cast<bf16x8*>(xb)[i] = o;
    }
  } else {
    const int n0 = (blockIdx.x - CVT_BLOCKS) * 8;
    __shared__ float bs[8][16];
    if (t < 128) bs[t >> 4][t & 15] = lB[(n0 + (t >> 4)) * 16 + (t & 15)] * LORA_SCALE;
    __syncthreads();
    for (int k0 = t * 4; k0 < Kdim; k0 += 1024) {
      float4 acc[8];
#pragma unroll
      for (int j = 0; j < 8; ++j)
        acc[j] = *reinterpret_cast<const float4*>(&W[(size_t)(n0 + j) * Kdim + k0]);
#pragma unroll
      for (int r = 0; r < 16; ++r) {
        float4 a = *reinterpret_cast<const float4*>(&lA[r * Kdim + k0]);
#pragma unroll
        for (int j = 0; j < 8; ++j) {
          acc[j].x += bs[j][r] * a.x;
          acc[j].y += bs[j][r] * a.y;
          acc[j].z += bs[j][r] * a.z;
          acc[j].w += bs[j][r] * a.w;
        }
      }
#pragma unroll
      for (int j = 0; j < 8; ++j) {
        bf16x4 o;
        o[0] = (bf16)acc[j].x; o[1] = (bf16)acc[j].y;
        o[2] = (bf16)acc[j].z; o[3] = (bf16)acc[j].w;
        *reinterpret_cast<bf16x4*>(&wb[(size_t)(n0 + j) * Kdim + k0]) = o;
      }
    }
  }
}

// ---------------- kernel 3: 256x256 bf16 MFMA GEMM, 32x32x16, 16 waves ----------------
// 16 waves (4M x 4N), per-wave 64x64 = 2x2 blocks of 32x32; K-tile 64 = 4 k-steps.
// LDS half = 16KB row-major: (r,k) at byte r*128 + ((k>>3)*16 ^ ((r&7)<<4)) + (k&7)*2.
// A-frag (32x32x16): lane l holds row l&31, k = (l>>5)*8 + j  (2xK ext of the
// verified 16x16x32 pattern); B symmetric. C/D: col=lane&31,
// row=(reg&3)+8*(reg>>2)+4*(lane>>5)  [HW-verified m74/m101].
// Schedule (r10/r16 pattern): ph0{B ks0 (4 rd) + A mi0 ks0 (2); stageA(t+1)h0; 4 MFMA}
//  ph1{B ks1 (4, pinned older) + A mi1 ks0 (2); stageA(t+1)h1; 4 MFMA} MIDBAR
//  ph2{A mi0 ks1 (2); stageB(t+2)h0; 4 MFMA} ph3{A mi1 ks1 (2); stageB(t+2)h1; 4 MFMA}
// Gate: vmcnt(2), vmcnt(0) at t=63; prologue 6 loads. W-A-R as r10 (B-reads
// confined to ph0/ph1; pin => b1 drained before mid-barrier).
__global__ __launch_bounds__(1024, 4) void gemm8(const bf16* __restrict__ Xb,
                                                 const bf16* __restrict__ Wb,
                                                 const float* __restrict__ bias,
                                                 float* __restrict__ out) {
  extern __shared__ char smem[];  // 131072 bytes
  const int tid = threadIdx.x;
  const int lane = tid & 63;
  const int wid = tid >> 6;               // 0..15
  const int wm = wid >> 2, wn = wid & 3;  // 4 x 4 wave grid
  const int l31 = lane & 31;
  const int hi = lane >> 5;  // 0..1

  // rectangular XCD chunking (512 wgs; xcd = wg&7; 8x8-tile chunks; bijective)
  const int wg = blockIdx.x;
  const int xcd = wg & 7;
  const int q = wg >> 3;  // 0..63
  const int bm0 = ((xcd >> 1) * 8 + (q & 7)) * 256;
  const int bn0 = ((xcd & 1) * 8 + (q >> 3)) * 256;

  // granule byte-in-row for k-step s (16 elems): ((s*32 + hi*16) ^ ((row&7)<<4));
  // row&7 == lane&7 for all our fragment rows (offsets are multiples of 8).
  const int sx = (lane & 7) << 4;
  int g[4];
#pragma unroll
  for (int s = 0; s < 4; ++s) g[s] = ((s * 32 + hi * 16) ^ sx);

  // fragment row-byte bases within a 64KB buffer
  int aAddr[2], bAddr[2];
#pragma unroll
  for (int mi = 0; mi < 2; ++mi)
    aAddr[mi] = (wm >> 1) * 16384 + ((wm & 1) * 64 + mi * 32 + l31) * 128;
#pragma unroll
  for (int nj = 0; nj < 2; ++nj)
    bAddr[nj] = 32768 + (wn >> 1) * 16384 + ((wn & 1) * 64 + nj * 32 + l31) * 128;

  // staging source: row r0 = tid>>3 within half, k-chunk c0 = (tid&7)^(r0&7)
  const int r0 = tid >> 3;   // 0..127
  const int c0 = (tid & 7) ^ (r0 & 7);
  const bf16* aSrc = Xb + (size_t)(bm0 + r0) * Kdim + c0 * 8;
  const bf16* bSrc = Wb + (size_t)(bn0 + r0) * Kdim + c0 * 8;
  const size_t halfJump = (size_t)128 * Kdim;

  auto stageA = [&](int kt, int h, char* buf) {
    gload_lds16(aSrc + h * halfJump + kt * 64, buf + h * 16384 + tid * 16);
  };
  auto stageB = [&](int kt, int h, char* buf) {
    gload_lds16(bSrc + h * halfJump + kt * 64, buf + 32768 + h * 16384 + tid * 16);
  };
#define ABUF(d) (smem + (d) * 65536)

  f32x16 acc[2][2] = {};
  bf16x8 aLo[2], aHi[2], b0[2][2], b1[2][2];

  // prologue: A(0), B(0) into buf0; B(1) into buf1  (6 loads)
  stageA(0, 0, ABUF(0));
  stageA(0, 1, ABUF(0));
  stageB(0, 0, ABUF(0));
  stageB(0, 1, ABUF(0));
  stageB(1, 0, ABUF(1));
  stageB(1, 1, ABUF(1));

  for (int t = 0; t < 64; ++t) {
    if (t == 63) {
      asm volatile("s_waitcnt vmcnt(0)" ::: "memory");
    } else {
      asm volatile("s_waitcnt vmcnt(2)" ::: "memory");
    }
    __builtin_amdgcn_s_barrier();
    char* Ab = ABUF(t & 1);

    // ---- ph0: B ks0 (nj x s{0,1}) + A mi0 ks0; stage A(t+1)h0 (other buffer)
#pragma unroll
    for (int nj = 0; nj < 2; ++nj)
#pragma unroll
      for (int s = 0; s < 2; ++s)
        b0[nj][s] = *reinterpret_cast<const bf16x8*>(Ab + bAddr[nj] + g[s]);
#pragma unroll
    for (int s = 0; s < 2; ++s)
      aLo[s] = *reinterpret_cast<const bf16x8*>(Ab + aAddr[0] + g[s]);
    if (t < 63) stageA(t + 1, 0, ABUF((t + 1) & 1));
    __builtin_amdgcn_s_setprio(1);
#pragma unroll
    for (int s = 0; s < 2; ++s)
#pragma unroll
      for (int nj = 0; nj < 2; ++nj)
        acc[0][nj] = __builtin_amdgcn_mfma_f32_32x32x16_bf16(aLo[s], b0[nj][s],
                                                             acc[0][nj], 0, 0, 0);
    __builtin_amdgcn_s_setprio(0);

    // ---- ph1: B ks1 FIRST (pinned older), then A mi1 ks0; stage A(t+1)h1.
    // In-order lgkm retirement: ph1's A-operand waits retire b1 too ->
    // all B-reads complete before the mid-barrier (stageB(t+2) W-A-R intact).
#pragma unroll
    for (int nj = 0; nj < 2; ++nj)
#pragma unroll
      for (int s = 0; s < 2; ++s)
        b1[nj][s] = *reinterpret_cast<const bf16x8*>(Ab + bAddr[nj] + g[2 + s]);
    __builtin_amdgcn_sched_barrier(0);  // pin: b1 issued before A mi1 reads
#pragma unroll
    for (int s = 0; s < 2; ++s)
      aHi[s] = *reinterpret_cast<const bf16x8*>(Ab + aAddr[1] + g[s]);
    if (t < 63) stageA(t + 1, 1, ABUF((t + 1) & 1));
    __builtin_amdgcn_s_setprio(1);
#pragma unroll
    for (int s = 0; s < 2; ++s)
#pragma unroll
      for (int nj = 0; nj < 2; ++nj)
        acc[1][nj] = __builtin_amdgcn_mfma_f32_32x32x16_bf16(aHi[s], b0[nj][s],
                                                             acc[1][nj], 0, 0, 0);
    __builtin_amdgcn_s_setprio(0);
    __builtin_amdgcn_s_barrier();  // mid: all B-reads of tile t retired block-wide

    // ---- ph2: A mi0 ks1; stage B(t+2)h0 (current buffer, B-region now free)
#pragma unroll
    for (int s = 0; s < 2; ++s)
      aLo[s] = *reinterpret_cast<const bf16x8*>(Ab + aAddr[0] + g[2 + s]);
    if (t < 62) stageB(t + 2, 0, Ab);
    __builtin_amdgcn_s_setprio(1);
#pragma unroll
    for (int s = 0; s < 2; ++s)
#pragma unroll
      for (int nj = 0; nj < 2; ++nj)
        acc[0][nj] = __builtin_amdgcn_mfma_f32_32x32x16_bf16(aLo[s], b1[nj][s],
                                                             acc[0][nj], 0, 0, 0);
    __builtin_amdgcn_s_setprio(0);

    // ---- ph3: A mi1 ks1; stage B(t+2)h1
#pragma unroll
    for (int s = 0; s < 2; ++s)
      aHi[s] = *reinterpret_cast<const bf16x8*>(Ab + aAddr[1] + g[2 + s]);
    if (t < 62) stageB(t + 2, 1, Ab);
    __builtin_amdgcn_s_setprio(1);
#pragma unroll
    for (int s = 0; s < 2; ++s)
#pragma unroll
      for (int nj = 0; nj < 2; ++nj)
        acc[1][nj] = __builtin_amdgcn_mfma_f32_32x32x16_bf16(aHi[s], b1[nj][s],
                                                             acc[1][nj], 0, 0, 0);
    __builtin_amdgcn_s_setprio(0);
  }

  // epilogue: C/D map col=lane&31, row=(reg&3)+8*(reg>>2)+4*(lane>>5)
  const int ccolW = bn0 + wn * 64 + l31;
  const int crowW = bm0 + wm * 64 + 4 * hi;
#pragma unroll
  for (int nj = 0; nj < 2; ++nj) {
    const int col = ccolW + nj * 32;
    const float bv = bias[col];
#pragma unroll
    for (int mi = 0; mi < 2; ++mi) {
      const int rb = crowW + mi * 32;
#pragma unroll
      for (int reg = 0; reg < 16; ++reg) {
        const int row = rb + (reg & 3) + 8 * (reg >> 2);
        out[(size_t)row * Ndim + col] = acc[mi][nj][reg] + bv;
      }
    }
  }
#undef ABUF
}

// ---------------- fallback (ws too small): fp32 tiled GEMM, fold on stage ----------------
__global__ __launch_bounds__(256) void gemm_fallback(const float* __restrict__ x,
                                                     const float* __restrict__ W,
                                                     const float* __restrict__ bias,
                                                     const float* __restrict__ lA,
                                                     const float* __restrict__ lB,
                                                     float* __restrict__ out) {
  __shared__ float xs[16][64];
  __shared__ float wt[16][64];
  const int t = threadIdx.x;
  const int tx = t & 15, ty = t >> 4;
  const int bm0 = blockIdx.y * 64, bn0 = blockIdx.x * 64;
  float acc[4][4] = {};
  for (int kt = 0; kt < Kdim; kt += 16) {
    __syncthreads();
    for (int e = t; e < 1024; e += 256) {
      int m = e >> 4, k = e & 15;
      xs[k][m] = x[(size_t)(bm0 + m) * Kdim + kt + k];
    }
    for (int e = t; e < 1024; e += 256) {
      int n = e >> 4, k = e & 15;
      float v = W[(size_t)(bn0 + n) * Kdim + kt + k];
#pragma unroll
      for (int r = 0; r < 16; ++r)
        v += LORA_SCALE * lB[(bn0 + n) * 16 + r] * lA[r * Kdim + kt + k];
      wt[k][n] = v;
    }
    __syncthreads();
#pragma unroll
    for (int k = 0; k < 16; ++k) {
      float xa[4], wv[4];
#pragma unroll
      for (int i = 0; i < 4; ++i) xa[i] = xs[k][ty * 4 + i];
#pragma unroll
      for (int j = 0; j < 4; ++j) wv[j] = wt[k][tx * 4 + j];
#pragma unroll
      for (int i = 0; i < 4; ++i)
#pragma unroll
        for (int j = 0; j < 4; ++j) acc[i][j] += xa[i] * wv[j];
    }
  }
#pragma unroll
  for (int i = 0; i < 4; ++i)
#pragma unroll
    for (int j = 0; j < 4; ++j)
      out[(size_t)(bm0 + ty * 4 + i) * Ndim + bn0 + tx * 4 + j] =
          acc[i][j] + bias[bn0 + tx * 4 + j];
}

extern "C" void kernel_launch(void* const* d_in, const int* in_sizes, int n_in,
                              void* d_out, int out_size, void* d_ws, size_t ws_size,
                              hipStream_t stream) {
  const float* x = (const float*)d_in[0];
  const float* W = (const float*)d_in[1];
  const float* b = (const float*)d_in[2];
  const float* lA = (const float*)d_in[3];
  const float* lB = (const float*)d_in[4];
  float* out = (float*)d_out;

  const size_t xb_bytes = (size_t)Mdim * Kdim * sizeof(bf16);
  const size_t wb_bytes = (size_t)Ndim * Kdim * sizeof(bf16);

  if (ws_size >= xb_bytes + wb_bytes) {
    bf16* xb = (bf16*)d_ws;
    bf16* wb = (bf16*)((char*)d_ws + xb_bytes);
    prep_kernel<<<CVT_BLOCKS + Ndim / 8, 256, 0, stream>>>(x, xb, W, lA, lB, wb);
    (void)hipFuncSetAttribute((const void*)gemm8,
                              hipFuncAttributeMaxDynamicSharedMemorySize, 131072);
    gemm8<<<dim3((Mdim / 256) * (Ndim / 256)), dim3(1024), 131072, stream>>>(xb, wb, b,
                                                                             out);
  } else {
    dim3 grid(Ndim / 64, Mdim / 64);
    gemm_fallback<<<grid, 64 * 4, 0, stream>>>(x, W, b, lA, lB, out);
  }
}

// Round 21
// 328.062 us; speedup vs baseline: 1.0744x; 1.0744x over previous
//
#include <hip/hip_runtime.h>

// LoRALinear: out = x @ (W + 2 * B@A)^T + b
// Final = r16 (HW-verified round 16: 328.8 µs total; GEMM 229 µs, MfmaUtil
// 57.3%, FETCH 200 MB, 0 bank conflicts): 16-wave 256² GEMM, 16x16x32 MFMA,
// row-major XOR-swizzle LDS, loose counted-wait schedule, rectangular XCD
// chunking, fused prep (cvt_x + W-fold).

static constexpr int Mdim = 8192;
static constexpr int Ndim = 4096;
static constexpr int Kdim = 4096;
#define LORA_SCALE 2.0f   // alpha/rank = 32/16

typedef __bf16 bf16;
typedef __bf16 bf16x8 __attribute__((ext_vector_type(8)));
typedef __bf16 bf16x4 __attribute__((ext_vector_type(4)));
typedef float f32x4 __attribute__((ext_vector_type(4)));

__device__ __forceinline__ void gload_lds16(const void* g, void* l) {
  __builtin_amdgcn_global_load_lds(
      (const __attribute__((address_space(1))) unsigned int*)g,
      (__attribute__((address_space(3))) unsigned int*)l, 16, 0, 0);
}

// ---------------- fused prep: blocks [0,4096) cvt x; [4096,4608) fold W' ----------------
static constexpr int CVT_BLOCKS = 4096;

__global__ __launch_bounds__(256) void prep_kernel(const float* __restrict__ x,
                                                   bf16* __restrict__ xb,
                                                   const float* __restrict__ W,
                                                   const float* __restrict__ lA,
                                                   const float* __restrict__ lB,
                                                   bf16* __restrict__ wb) {
  const int t = threadIdx.x;
  if (blockIdx.x < CVT_BLOCKS) {
    const int n8 = Mdim * Kdim / 8;
    for (int i = blockIdx.x * 256 + t; i < n8; i += CVT_BLOCKS * 256) {
      const float4* p = reinterpret_cast<const float4*>(x) + (size_t)i * 2;
      float4 a = p[0];
      float4 c = p[1];
      bf16x8 o;
      o[0] = (bf16)a.x; o[1] = (bf16)a.y; o[2] = (bf16)a.z; o[3] = (bf16)a.w;
      o[4] = (bf16)c.x; o[5] = (bf16)c.y; o[6] = (bf16)c.z; o[7] = (bf16)c.w;
      reinterpret_cast<bf16x8*>(xb)[i] = o;
    }
  } else {
    const int n0 = (blockIdx.x - CVT_BLOCKS) * 8;
    __shared__ float bs[8][16];
    if (t < 128) bs[t >> 4][t & 15] = lB[(n0 + (t >> 4)) * 16 + (t & 15)] * LORA_SCALE;
    __syncthreads();
    for (int k0 = t * 4; k0 < Kdim; k0 += 1024) {
      float4 acc[8];
#pragma unroll
      for (int j = 0; j < 8; ++j)
        acc[j] = *reinterpret_cast<const float4*>(&W[(size_t)(n0 + j) * Kdim + k0]);
#pragma unroll
      for (int r = 0; r < 16; ++r) {
        float4 a = *reinterpret_cast<const float4*>(&lA[r * Kdim + k0]);
#pragma unroll
        for (int j = 0; j < 8; ++j) {
          acc[j].x += bs[j][r] * a.x;
          acc[j].y += bs[j][r] * a.y;
          acc[j].z += bs[j][r] * a.z;
          acc[j].w += bs[j][r] * a.w;
        }
      }
#pragma unroll
      for (int j = 0; j < 8; ++j) {
        bf16x4 o;
        o[0] = (bf16)acc[j].x; o[1] = (bf16)acc[j].y;
        o[2] = (bf16)acc[j].z; o[3] = (bf16)acc[j].w;
        *reinterpret_cast<bf16x4*>(&wb[(size_t)(n0 + j) * Kdim + k0]) = o;
      }
    }
  }
}

// ---------------- kernel 3: 256x256 bf16 MFMA GEMM, 16 waves, XCD-chunked ----------------
// 16 waves (4M x 4N), per-wave 64x64. BK=64, 64 K-tiles, dbuf by K-tile (128KB).
// LDS half = 16KB row-major: (r,k) at byte r*128 + ((k>>3)*16 ^ ((r&7)<<4)) + (k&7)*2.
// XCD chunking: wg -> xcd = wg&7 (round-robin dispatch), q = wg>>3; each XCD
// owns an 8x8 tile chunk -> per-XCD reads 8 A-panels + 8 B-panels = 32 MB.
// Schedule (r10 pattern, 16-wave): ph0{b0,a0lo; stageA(t+1)h0; MFMA}
//  ph1{b1 pinned, a0hi; stageA(t+1)h1; MFMA} MIDBAR
//  ph2{a1lo; stageB(t+2)h0; MFMA} ph3{a1hi; stageB(t+2)h1; MFMA}
// Gate: vmcnt(2) (leaves B(t+1)'s 2 loads), vmcnt(0) at t=63. Prologue 6 loads.
__global__ __launch_bounds__(1024, 4) void gemm8(const bf16* __restrict__ Xb,
                                                 const bf16* __restrict__ Wb,
                                                 const float* __restrict__ bias,
                                                 float* __restrict__ out) {
  extern __shared__ char smem[];  // 131072 bytes
  const int tid = threadIdx.x;
  const int lane = tid & 63;
  const int wid = tid >> 6;               // 0..15
  const int wm = wid >> 2, wn = wid & 3;  // 4 x 4 wave grid
  const int r16 = lane & 15;
  const int kq = lane >> 4;  // 0..3

  // rectangular XCD chunking (512 wgs = 32M x 16N tiles; 8 XCDs x 64 wgs):
  // xcd chunk grid 4M x 2N, chunk = 8x8 tiles. Bijective.
  const int wg = blockIdx.x;
  const int xcd = wg & 7;
  const int q = wg >> 3;  // 0..63
  const int bm0 = ((xcd >> 1) * 8 + (q & 7)) * 256;
  const int bn0 = ((xcd & 1) * 8 + (q >> 3)) * 256;

  // fragment byte bases within a 64KB buffer (+mi/nj*2048 later)
  const int sx = (r16 & 7) << 4;
  const int aRow = (wm >> 1) * 16384 + ((wm & 1) * 64 + r16) * 128;
  const int bRow = 32768 + (wn >> 1) * 16384 + ((wn & 1) * 64 + r16) * 128;
  const int g0 = (kq * 16) ^ sx;        // ks0 granule byte-in-row
  const int g1 = (64 + kq * 16) ^ sx;   // ks1
  const int aBase0 = aRow + g0, aBase1 = aRow + g1;
  const int bBase0 = bRow + g0, bBase1 = bRow + g1;

  // staging source: row r0 = tid>>3 within half, k-chunk c0 = (tid&7)^(r0&7)
  const int r0 = tid >> 3;   // 0..127
  const int c0 = (tid & 7) ^ (r0 & 7);
  const bf16* aSrc = Xb + (size_t)(bm0 + r0) * Kdim + c0 * 8;
  const bf16* bSrc = Wb + (size_t)(bn0 + r0) * Kdim + c0 * 8;
  const size_t halfJump = (size_t)128 * Kdim;

  auto stageA = [&](int kt, int h, char* buf) {
    gload_lds16(aSrc + h * halfJump + kt * 64, buf + h * 16384 + tid * 16);
  };
  auto stageB = [&](int kt, int h, char* buf) {
    gload_lds16(bSrc + h * halfJump + kt * 64, buf + 32768 + h * 16384 + tid * 16);
  };
#define ABUF(d) (smem + (d) * 65536)

  f32x4 acc[4][4] = {};
  bf16x8 a0[4], a1[4], b0[4], b1[4];

  // prologue: A(0), B(0) into buf0; B(1) into buf1  (6 loads)
  stageA(0, 0, ABUF(0));
  stageA(0, 1, ABUF(0));
  stageB(0, 0, ABUF(0));
  stageB(0, 1, ABUF(0));
  stageB(1, 0, ABUF(1));
  stageB(1, 1, ABUF(1));

  for (int t = 0; t < 64; ++t) {
    if (t == 63) {
      asm volatile("s_waitcnt vmcnt(0)" ::: "memory");
    } else {
      asm volatile("s_waitcnt vmcnt(2)" ::: "memory");
    }
    __builtin_amdgcn_s_barrier();
    char* Ab = ABUF(t & 1);

    // ---- ph0: b(ks0) x4 + a(ks0) mi0-1; stage A(t+1)h0 (other buffer)
#pragma unroll
    for (int nj = 0; nj < 4; ++nj)
      b0[nj] = *reinterpret_cast<const bf16x8*>(Ab + bBase0 + nj * 2048);
#pragma unroll
    for (int mi = 0; mi < 2; ++mi)
      a0[mi] = *reinterpret_cast<const bf16x8*>(Ab + aBase0 + mi * 2048);
    if (t < 63) stageA(t + 1, 0, ABUF((t + 1) & 1));
    __builtin_amdgcn_s_setprio(1);
#pragma unroll
    for (int mi = 0; mi < 2; ++mi)
#pragma unroll
      for (int nj = 0; nj < 4; ++nj)
        acc[mi][nj] = __builtin_amdgcn_mfma_f32_16x16x32_bf16(a0[mi], b0[nj],
                                                              acc[mi][nj], 0, 0, 0);
    __builtin_amdgcn_s_setprio(0);

    // ---- ph1: b(ks1) FIRST (pinned older), then a(ks0) mi2-3; stage A(t+1)h1.
    // In-order lgkm retirement: ph1's a0hi operand waits retire b1 too ->
    // all B-reads complete before the mid-barrier (stageB(t+2) W-A-R intact).
#pragma unroll
    for (int nj = 0; nj < 4; ++nj)
      b1[nj] = *reinterpret_cast<const bf16x8*>(Ab + bBase1 + nj * 2048);
    __builtin_amdgcn_sched_barrier(0);  // pin: b1 issued before a0hi
#pragma unroll
    for (int mi = 2; mi < 4; ++mi)
      a0[mi] = *reinterpret_cast<const bf16x8*>(Ab + aBase0 + mi * 2048);
    if (t < 63) stageA(t + 1, 1, ABUF((t + 1) & 1));
    __builtin_amdgcn_s_setprio(1);
#pragma unroll
    for (int mi = 2; mi < 4; ++mi)
#pragma unroll
      for (int nj = 0; nj < 4; ++nj)
        acc[mi][nj] = __builtin_amdgcn_mfma_f32_16x16x32_bf16(a0[mi], b0[nj],
                                                              acc[mi][nj], 0, 0, 0);
    __builtin_amdgcn_s_setprio(0);
    __builtin_amdgcn_s_barrier();  // mid: all B-reads of tile t retired block-wide

    // ---- ph2: a(ks1) mi0-1; stage B(t+2)h0 (current buffer, B-region free)
#pragma unroll
    for (int mi = 0; mi < 2; ++mi)
      a1[mi] = *reinterpret_cast<const bf16x8*>(Ab + aBase1 + mi * 2048);
    if (t < 62) stageB(t + 2, 0, Ab);
    __builtin_amdgcn_s_setprio(1);
#pragma unroll
    for (int mi = 0; mi < 2; ++mi)
#pragma unroll
      for (int nj = 0; nj < 4; ++nj)
        acc[mi][nj] = __builtin_amdgcn_mfma_f32_16x16x32_bf16(a1[mi], b1[nj],
                                                              acc[mi][nj], 0, 0, 0);
    __builtin_amdgcn_s_setprio(0);

    // ---- ph3: a(ks1) mi2-3; stage B(t+2)h1
#pragma unroll
    for (int mi = 2; mi < 4; ++mi)
      a1[mi] = *reinterpret_cast<const bf16x8*>(Ab + aBase1 + mi * 2048);
    if (t < 62) stageB(t + 2, 1, Ab);
    __builtin_amdgcn_s_setprio(1);
#pragma unroll
    for (int mi = 2; mi < 4; ++mi)
#pragma unroll
      for (int nj = 0; nj < 4; ++nj)
        acc[mi][nj] = __builtin_amdgcn_mfma_f32_16x16x32_bf16(a1[mi], b1[nj],
                                                              acc[mi][nj], 0, 0, 0);
    __builtin_amdgcn_s_setprio(0);
  }

  // epilogue: C/D map col=lane&15, row=(lane>>4)*4+reg
  const int crow0 = bm0 + wm * 64 + (lane >> 4) * 4;
  const int ccol0 = bn0 + wn * 64 + r16;
#pragma unroll
  for (int nj = 0; nj < 4; ++nj) {
    float bv = bias[ccol0 + nj * 16];
#pragma unroll
    for (int mi = 0; mi < 4; ++mi)
#pragma unroll
      for (int r = 0; r < 4; ++r)
        out[(size_t)(crow0 + mi * 16 + r) * Ndim + ccol0 + nj * 16] =
            acc[mi][nj][r] + bv;
  }
#undef ABUF
}

// ---------------- fallback (ws too small): fp32 tiled GEMM, fold on stage ----------------
__global__ __launch_bounds__(256) void gemm_fallback(const float* __restrict__ x,
                                                     const float* __restrict__ W,
                                                     const float* __restrict__ bias,
                                                     const float* __restrict__ lA,
                                                     const float* __restrict__ lB,
                                                     float* __restrict__ out) {
  __shared__ float xs[16][64];
  __shared__ float wt[16][64];
  const int t = threadIdx.x;
  const int tx = t & 15, ty = t >> 4;
  const int bm0 = blockIdx.y * 64, bn0 = blockIdx.x * 64;
  float acc[4][4] = {};
  for (int kt = 0; kt < Kdim; kt += 16) {
    __syncthreads();
    for (int e = t; e < 1024; e += 256) {
      int m = e >> 4, k = e & 15;
      xs[k][m] = x[(size_t)(bm0 + m) * Kdim + kt + k];
    }
    for (int e = t; e < 1024; e += 256) {
      int n = e >> 4, k = e & 15;
      float v = W[(size_t)(bn0 + n) * Kdim + kt + k];
#pragma unroll
      for (int r = 0; r < 16; ++r)
        v += LORA_SCALE * lB[(bn0 + n) * 16 + r] * lA[r * Kdim + kt + k];
      wt[k][n] = v;
    }
    __syncthreads();
#pragma unroll
    for (int k = 0; k < 16; ++k) {
      float xa[4], wv[4];
#pragma unroll
      for (int i = 0; i < 4; ++i) xa[i] = xs[k][ty * 4 + i];
#pragma unroll
      for (int j = 0; j < 4; ++j) wv[j] = wt[k][tx * 4 + j];
#pragma unroll
      for (int i = 0; i < 4; ++i)
#pragma unroll
        for (int j = 0; j < 4; ++j) acc[i][j] += xa[i] * wv[j];
    }
  }
#pragma unroll
  for (int i = 0; i < 4; ++i)
#pragma unroll
    for (int j = 0; j < 4; ++j)
      out[(size_t)(bm0 + ty * 4 + i) * Ndim + bn0 + tx * 4 + j] =
          acc[i][j] + bias[bn0 + tx * 4 + j];
}

extern "C" void kernel_launch(void* const* d_in, const int* in_sizes, int n_in,
                              void* d_out, int out_size, void* d_ws, size_t ws_size,
                              hipStream_t stream) {
  const float* x = (const float*)d_in[0];
  const float* W = (const float*)d_in[1];
  const float* b = (const float*)d_in[2];
  const float* lA = (const float*)d_in[3];
  const float* lB = (const float*)d_in[4];
  float* out = (float*)d_out;

  const size_t xb_bytes = (size_t)Mdim * Kdim * sizeof(bf16);
  const size_t wb_bytes = (size_t)Ndim * Kdim * sizeof(bf16);

  if (ws_size >= xb_bytes + wb_bytes) {
    bf16* xb = (bf16*)d_ws;
    bf16* wb = (bf16*)((char*)d_ws + xb_bytes);
    prep_kernel<<<CVT_BLOCKS + Ndim / 8, 256, 0, stream>>>(x, xb, W, lA, lB, wb);
    (void)hipFuncSetAttribute((const void*)gemm8,
                              hipFuncAttributeMaxDynamicSharedMemorySize, 131072);
    gemm8<<<dim3((Mdim / 256) * (Ndim / 256)), dim3(1024), 131072, stream>>>(xb, wb, b,
                                                                             out);
  } else {
    dim3 grid(Ndim / 64, Mdim / 64);
    gemm_fallback<<<grid, 64 * 4, 0, stream>>>(x, W, b, lA, lB, out);
  }
}